// Round 4
// baseline (248.256 us; speedup 1.0000x reference)
//
#include <hip/hip_runtime.h>
#include <hip/hip_bf16.h>

#define BS    128
#define NCIN  64
#define NCOUT 64
#define LLEN  8192
#define NK    3
#define NR    8
#define NEMB  256
#define NHID  256
#define WPS   (NCOUT * NCIN * NK)   // 12288 weights per sample
#define NT    256                   // l-positions per conv block

typedef __attribute__((ext_vector_type(4))) float f32x4;
typedef __attribute__((ext_vector_type(8))) __bf16 bf16x8;

// Static scratch: effective per-sample conv weights (bf16), layout [b][k][co][ci].
// 128 * 12288 * 2 B = 3 MB. Fully rewritten every call.
__device__ __bf16 g_Wb[BS * WPS];

// ---------------------------------------------------------------------------
// Kernel 1: both MLPs -> W_eff(bf16) = base_w + A·B, stored [b][k][co][ci].
// (This fused path was empirically verified equal to the naive 5-kernel path:
//  identical decimated readback signatures in rounds 1-3.)
// ---------------------------------------------------------------------------
__global__ __launch_bounds__(256) void factors_kernel(
    const float* __restrict__ a_emb, const float* __restrict__ b_emb,
    const float* __restrict__ A_w1, const float* __restrict__ A_b1,
    const float* __restrict__ A_g,  const float* __restrict__ A_beta,
    const float* __restrict__ A_w2, const float* __restrict__ A_b2,
    const float* __restrict__ B_w1, const float* __restrict__ B_b1,
    const float* __restrict__ B_g,  const float* __restrict__ B_beta,
    const float* __restrict__ B_w2, const float* __restrict__ B_b2,
    const float* __restrict__ base_w)
{
    __shared__ __align__(16) float emb_s[4][NEMB];
    __shared__ __align__(16) float h_s[4][NHID];
    __shared__ __align__(16) float Af[4][512];
    __shared__ __align__(16) float Bf[4][1536];

    const int t  = threadIdx.x;
    const int b0 = blockIdx.x * 4;
    const float bn_scale_const = 1.0f / sqrtf(1.0f + 1e-5f);

    for (int s = 0; s < 4; ++s) emb_s[s][t] = a_emb[(size_t)(b0 + s) * NEMB + t];
    __syncthreads();

    // branch A hidden: Linear + BN(eval) + exact GELU
    {
        float acc[4];
        const float bi = A_b1[t];
        for (int s = 0; s < 4; ++s) acc[s] = bi;
        const f32x4* wr = (const f32x4*)(A_w1 + (size_t)t * NEMB);
        for (int e = 0; e < NEMB / 4; ++e) {
            f32x4 w = wr[e];
            #pragma unroll
            for (int s = 0; s < 4; ++s) {
                f32x4 a = ((const f32x4*)emb_s[s])[e];
                acc[s] += w[0]*a[0] + w[1]*a[1] + w[2]*a[2] + w[3]*a[3];
            }
        }
        const float gs = A_g[t] * bn_scale_const;
        const float bt = A_beta[t];
        #pragma unroll
        for (int s = 0; s < 4; ++s) {
            float h = acc[s] * gs + bt;
            h = 0.5f * h * (1.0f + erff(h * 0.70710678118654752f));
            h_s[s][t] = h;
        }
    }
    __syncthreads();

    // branch A outputs (512); preload b embeddings
    for (int s = 0; s < 4; ++s) emb_s[s][t] = b_emb[(size_t)(b0 + s) * NEMB + t];
    for (int oo = 0; oo < 2; ++oo) {
        const int o = oo * 256 + t;
        float acc[4];
        const float bi = A_b2[o];
        for (int s = 0; s < 4; ++s) acc[s] = bi;
        const f32x4* wr = (const f32x4*)(A_w2 + (size_t)o * NHID);
        for (int e = 0; e < NHID / 4; ++e) {
            f32x4 w = wr[e];
            #pragma unroll
            for (int s = 0; s < 4; ++s) {
                f32x4 h = ((const f32x4*)h_s[s])[e];
                acc[s] += w[0]*h[0] + w[1]*h[1] + w[2]*h[2] + w[3]*h[3];
            }
        }
        for (int s = 0; s < 4; ++s) Af[s][o] = acc[s];
    }
    __syncthreads();

    // branch B hidden
    {
        float acc[4];
        const float bi = B_b1[t];
        for (int s = 0; s < 4; ++s) acc[s] = bi;
        const f32x4* wr = (const f32x4*)(B_w1 + (size_t)t * NEMB);
        for (int e = 0; e < NEMB / 4; ++e) {
            f32x4 w = wr[e];
            #pragma unroll
            for (int s = 0; s < 4; ++s) {
                f32x4 a = ((const f32x4*)emb_s[s])[e];
                acc[s] += w[0]*a[0] + w[1]*a[1] + w[2]*a[2] + w[3]*a[3];
            }
        }
        const float gs = B_g[t] * bn_scale_const;
        const float bt = B_beta[t];
        #pragma unroll
        for (int s = 0; s < 4; ++s) {
            float h = acc[s] * gs + bt;
            h = 0.5f * h * (1.0f + erff(h * 0.70710678118654752f));
            h_s[s][t] = h;
        }
    }
    __syncthreads();

    // branch B outputs (1536)
    for (int oo = 0; oo < 6; ++oo) {
        const int o = oo * 256 + t;
        float acc[4];
        const float bi = B_b2[o];
        for (int s = 0; s < 4; ++s) acc[s] = bi;
        const f32x4* wr = (const f32x4*)(B_w2 + (size_t)o * NHID);
        for (int e = 0; e < NHID / 4; ++e) {
            f32x4 w = wr[e];
            #pragma unroll
            for (int s = 0; s < 4; ++s) {
                f32x4 h = ((const f32x4*)h_s[s])[e];
                acc[s] += w[0]*h[0] + w[1]*h[1] + w[2]*h[2] + w[3]*h[3];
            }
        }
        for (int s = 0; s < 4; ++s) Bf[s][o] = acc[s];
    }
    __syncthreads();

    // W_eff[co][ci][k] = base_w[co][ci][k] + sum_r A[ci][r]*B[r][co*3+k]
    // stored as g_Wb[b][k][co][ci]
    const int ci = t & 63;
    for (int s = 0; s < 4; ++s) {
        float Ar[NR];
        #pragma unroll
        for (int r = 0; r < NR; ++r) Ar[r] = Af[s][ci * NR + r];
        for (int i = 0; i < 48; ++i) {
            const int w  = t + i * 256;     // enumerates k*4096 + co*64 + ci
            const int k  = w >> 12;
            const int co = (w >> 6) & 63;
            float v = base_w[(size_t)(co * 64 + ci) * 3 + k];
            #pragma unroll
            for (int r = 0; r < NR; ++r) v += Ar[r] * Bf[s][r * 192 + co * 3 + k];
            g_Wb[(size_t)(b0 + s) * WPS + k * 4096 + co * 64 + ci] = (__bf16)v;
        }
    }
}

// ---------------------------------------------------------------------------
// Kernel 2: per-sample conv as MFMA GEMM (round-1 structure, f32 epilogue).
// Block = (b, 256-l tile); LDS: X tile transposed [lp][ci] bf16, XOR-swizzled.
// ---------------------------------------------------------------------------
__global__ __launch_bounds__(256) void conv_kernel(
    const float* __restrict__ X, const float* __restrict__ base_b,
    float* __restrict__ out)
{
    __shared__ __align__(16) __bf16 xt[(NT + 2) * 64];

    const int t    = threadIdx.x;
    const int b    = blockIdx.x >> 5;    // 32 tiles per sample
    const int tile = blockIdx.x & 31;
    const int l0   = tile * NT;
    const int lane = t & 63;
    const int wave = t >> 6;
    const int g    = lane >> 4;
    const int l15  = lane & 15;
    const int wco  = wave >> 1;          // which 32 co
    const int wl   = wave & 1;           // which 128 l

    // A fragments (weights) into registers
    bf16x8 af[2][6];
    {
        const __bf16* wb = g_Wb + (size_t)b * WPS;
        #pragma unroll
        for (int m = 0; m < 2; ++m)
            #pragma unroll
            for (int kk = 0; kk < 6; ++kk) {
                const int k = kk >> 1, s2 = kk & 1;
                const int co = wco * 32 + m * 16 + l15;
                const int cc = s2 * 32 + g * 8;
                af[m][kk] = *(const bf16x8*)(wb + k * 4096 + co * 64 + cc);
            }
    }

    // stage X tile (transposed + swizzled, f32 -> bf16)
    for (int p = 0; p < 16; ++p) {
        const int ci = p * 4 + (t >> 6);
        const int f4 = t & 63;
        f32x4 v = *(const f32x4*)(X + (size_t)(b * NCIN + ci) * LLEN + l0 + f4 * 4);
        #pragma unroll
        for (int j = 0; j < 4; ++j) {
            const int lp = f4 * 4 + j + 1;
            xt[lp * 64 + (((ci >> 3) ^ (lp & 7)) << 3) + (ci & 7)] = (__bf16)v[j];
        }
    }
    if (t < 128) {  // halo columns (pad = 1)
        const int ci    = t & 63;
        const int right = t >> 6;
        const int gl    = right ? (l0 + NT) : (l0 - 1);
        const int lp    = right ? (NT + 1) : 0;
        const float v   = (gl >= 0 && gl < LLEN) ? X[(size_t)(b * NCIN + ci) * LLEN + gl] : 0.0f;
        xt[lp * 64 + (((ci >> 3) ^ (lp & 7)) << 3) + (ci & 7)] = (__bf16)v;
    }
    __syncthreads();

    // MFMA main: contraction over 3 taps x 64 ci
    f32x4 acc[2][8] = {};
    #pragma unroll
    for (int kk = 0; kk < 6; ++kk) {
        const int k = kk >> 1, s2 = kk & 1;
        #pragma unroll
        for (int n = 0; n < 8; ++n) {
            const int lp  = wl * 128 + n * 16 + l15 + k;   // tap-shifted row
            const int blk = (s2 * 4 + g) ^ (lp & 7);
            bf16x8 bfr = *(const bf16x8*)(xt + lp * 64 + blk * 8);
            acc[0][n] = __builtin_amdgcn_mfma_f32_16x16x32_bf16(af[0][kk], bfr, acc[0][n], 0, 0, 0);
            acc[1][n] = __builtin_amdgcn_mfma_f32_16x16x32_bf16(af[1][kk], bfr, acc[1][n], 0, 0, 0);
        }
    }

    // epilogue: + base_b, store f32 (reference output dtype)
    #pragma unroll
    for (int m = 0; m < 2; ++m) {
        const int co0 = wco * 32 + m * 16 + g * 4;
        #pragma unroll
        for (int j = 0; j < 4; ++j) {
            const float bb = base_b[co0 + j];
            float* op = out + (size_t)(b * NCOUT + co0 + j) * LLEN + l0 + wl * 128 + l15;
            #pragma unroll
            for (int n = 0; n < 8; ++n)
                op[n * 16] = acc[m][n][j] + bb;
        }
    }
}

// ---------------------------------------------------------------------------
extern "C" void kernel_launch(void* const* d_in, const int* in_sizes, int n_in,
                              void* d_out, int out_size, void* d_ws, size_t ws_size,
                              hipStream_t stream)
{
    const float* X      = (const float*)d_in[0];
    const float* a_emb  = (const float*)d_in[1];
    const float* b_emb  = (const float*)d_in[2];
    const float* A_w1   = (const float*)d_in[3];
    const float* A_b1   = (const float*)d_in[4];
    const float* A_g    = (const float*)d_in[5];
    const float* A_beta = (const float*)d_in[6];
    const float* A_w2   = (const float*)d_in[7];
    const float* A_b2   = (const float*)d_in[8];
    const float* B_w1   = (const float*)d_in[9];
    const float* B_b1   = (const float*)d_in[10];
    const float* B_g    = (const float*)d_in[11];
    const float* B_beta = (const float*)d_in[12];
    const float* B_w2   = (const float*)d_in[13];
    const float* B_b2   = (const float*)d_in[14];
    const float* base_w = (const float*)d_in[15];
    const float* base_b = (const float*)d_in[16];

    float* out = (float*)d_out;   // reference output dtype is float32

    factors_kernel<<<BS / 4, 256, 0, stream>>>(a_emb, b_emb,
        A_w1, A_b1, A_g, A_beta, A_w2, A_b2,
        B_w1, B_b1, B_g, B_beta, B_w2, B_b2,
        base_w);

    conv_kernel<<<BS * (LLEN / NT), 256, 0, stream>>>(X, base_b, out);
}

// Round 5
// 234.302 us; speedup vs baseline: 1.0596x; 1.0596x over previous
//
#include <hip/hip_runtime.h>
#include <hip/hip_bf16.h>

#define BS    128
#define NCIN  64
#define NCOUT 64
#define LLEN  8192
#define NK    3
#define NR    8
#define NEMB  256
#define NHID  256
#define WPS   (NCOUT * NCIN * NK)   // 12288 weights per sample
#define NT    256                   // l-positions per conv block

typedef __attribute__((ext_vector_type(4))) float f32x4;
typedef __attribute__((ext_vector_type(8))) __bf16 bf16x8;

// Static scratch: effective per-sample conv weights (bf16), layout [b][k][co][ci].
__device__ __bf16 g_Wb[BS * WPS];

// ---------------------------------------------------------------------------
// Kernel 1: both MLPs -> W_eff(bf16) = base_w + A·B, stored [b][k][co][ci].
// One sample per block (128 blocks) for CU parallelism.
// ---------------------------------------------------------------------------
__global__ __launch_bounds__(256) void factors_kernel(
    const float* __restrict__ a_emb, const float* __restrict__ b_emb,
    const float* __restrict__ A_w1, const float* __restrict__ A_b1,
    const float* __restrict__ A_g,  const float* __restrict__ A_beta,
    const float* __restrict__ A_w2, const float* __restrict__ A_b2,
    const float* __restrict__ B_w1, const float* __restrict__ B_b1,
    const float* __restrict__ B_g,  const float* __restrict__ B_beta,
    const float* __restrict__ B_w2, const float* __restrict__ B_b2,
    const float* __restrict__ base_w)
{
    __shared__ __align__(16) float emb_s[NEMB];
    __shared__ __align__(16) float h_s[NHID];
    __shared__ __align__(16) float Af[512];
    __shared__ __align__(16) float Bf[1536];

    const int t = threadIdx.x;
    const int b = blockIdx.x;
    const float bn_scale_const = 1.0f / sqrtf(1.0f + 1e-5f);

    emb_s[t] = a_emb[(size_t)b * NEMB + t];
    __syncthreads();

    // branch A hidden: Linear + BN(eval) + exact GELU
    {
        float acc = A_b1[t];
        const f32x4* wr = (const f32x4*)(A_w1 + (size_t)t * NEMB);
        const f32x4* es = (const f32x4*)emb_s;
        for (int e = 0; e < NEMB / 4; ++e) {
            f32x4 w = wr[e], a = es[e];
            acc += w[0]*a[0] + w[1]*a[1] + w[2]*a[2] + w[3]*a[3];
        }
        float h = acc * (A_g[t] * bn_scale_const) + A_beta[t];
        h = 0.5f * h * (1.0f + erff(h * 0.70710678118654752f));
        h_s[t] = h;
    }
    __syncthreads();

    // branch A outputs (512); preload b embedding (emb_s free now)
    emb_s[t] = b_emb[(size_t)b * NEMB + t];
    for (int oo = 0; oo < 2; ++oo) {
        const int o = oo * 256 + t;
        float acc = A_b2[o];
        const f32x4* wr = (const f32x4*)(A_w2 + (size_t)o * NHID);
        const f32x4* hs = (const f32x4*)h_s;
        for (int e = 0; e < NHID / 4; ++e) {
            f32x4 w = wr[e], h = hs[e];
            acc += w[0]*h[0] + w[1]*h[1] + w[2]*h[2] + w[3]*h[3];
        }
        Af[o] = acc;
    }
    __syncthreads();

    // branch B hidden
    {
        float acc = B_b1[t];
        const f32x4* wr = (const f32x4*)(B_w1 + (size_t)t * NEMB);
        const f32x4* es = (const f32x4*)emb_s;
        for (int e = 0; e < NEMB / 4; ++e) {
            f32x4 w = wr[e], a = es[e];
            acc += w[0]*a[0] + w[1]*a[1] + w[2]*a[2] + w[3]*a[3];
        }
        float h = acc * (B_g[t] * bn_scale_const) + B_beta[t];
        h = 0.5f * h * (1.0f + erff(h * 0.70710678118654752f));
        __syncthreads();          // Af reads of h_s done before overwrite
        h_s[t] = h;
    }
    __syncthreads();

    // branch B outputs (1536)
    for (int oo = 0; oo < 6; ++oo) {
        const int o = oo * 256 + t;
        float acc = B_b2[o];
        const f32x4* wr = (const f32x4*)(B_w2 + (size_t)o * NHID);
        const f32x4* hs = (const f32x4*)h_s;
        for (int e = 0; e < NHID / 4; ++e) {
            f32x4 w = wr[e], h = hs[e];
            acc += w[0]*h[0] + w[1]*h[1] + w[2]*h[2] + w[3]*h[3];
        }
        Bf[o] = acc;
    }
    __syncthreads();

    // W_eff[co][ci][k] = base_w[co][ci][k] + sum_r A[ci][r]*B[r][co*3+k]
    // stored as g_Wb[b][k][co][ci]
    const int ci = t & 63;   // constant across i (stride 256 ≡ 0 mod 64)
    float Ar[NR];
    #pragma unroll
    for (int r = 0; r < NR; ++r) Ar[r] = Af[ci * NR + r];
    for (int i = 0; i < 48; ++i) {
        const int w  = t + i * 256;     // enumerates k*4096 + co*64 + ci
        const int k  = w >> 12;
        const int co = (w >> 6) & 63;
        float v = base_w[(size_t)(co * 64 + ci) * 3 + k];
        #pragma unroll
        for (int r = 0; r < NR; ++r) v += Ar[r] * Bf[r * 192 + co * 3 + k];
        g_Wb[(size_t)b * WPS + w] = (__bf16)v;
    }
}

// ---------------------------------------------------------------------------
// Kernel 2: per-sample conv as MFMA GEMM. Block = (b, 256-l tile).
// LDS: X tile transposed [lp][ci] bf16 (XOR-swizzled); reused as f32 [32][258]
// for the coalesced-store epilogue.
// ---------------------------------------------------------------------------
__global__ __launch_bounds__(256) void conv_kernel(
    const float* __restrict__ X, const float* __restrict__ base_b,
    float* __restrict__ out)
{
    __shared__ __align__(16) unsigned char smem[33024];  // = (NT+2)*64*2 = 32*258*4
    __bf16* xt = (__bf16*)smem;
    float*  ot = (float*)smem;

    const int t    = threadIdx.x;
    const int b    = blockIdx.x >> 5;    // 32 tiles per sample
    const int tile = blockIdx.x & 31;
    const int l0   = tile * NT;
    const int lane = t & 63;
    const int wave = t >> 6;
    const int g    = lane >> 4;
    const int l15  = lane & 15;
    const int wco  = wave >> 1;          // which 32 co
    const int wl   = wave & 1;           // which 128 l

    // A fragments (weights) into registers
    bf16x8 af[2][6];
    {
        const __bf16* wb = g_Wb + (size_t)b * WPS;
        #pragma unroll
        for (int m = 0; m < 2; ++m)
            #pragma unroll
            for (int kk = 0; kk < 6; ++kk) {
                const int k = kk >> 1, s2 = kk & 1;
                const int co = wco * 32 + m * 16 + l15;
                const int cc = s2 * 32 + g * 8;
                af[m][kk] = *(const bf16x8*)(wb + k * 4096 + co * 64 + cc);
            }
    }

    // stage X tile (transposed + swizzled, f32 -> bf16)
    for (int p = 0; p < 16; ++p) {
        const int ci = p * 4 + wave;
        const int f4 = lane;
        f32x4 v = *(const f32x4*)(X + (size_t)(b * NCIN + ci) * LLEN + l0 + f4 * 4);
        #pragma unroll
        for (int j = 0; j < 4; ++j) {
            const int lp = f4 * 4 + j + 1;
            xt[lp * 64 + (((ci >> 3) ^ (lp & 7)) << 3) + (ci & 7)] = (__bf16)v[j];
        }
    }
    if (t < 128) {  // halo columns (pad = 1)
        const int ci    = t & 63;
        const int right = t >> 6;
        const int gl    = right ? (l0 + NT) : (l0 - 1);
        const int lp    = right ? (NT + 1) : 0;
        const float v   = (gl >= 0 && gl < LLEN) ? X[(size_t)(b * NCIN + ci) * LLEN + gl] : 0.0f;
        xt[lp * 64 + (((ci >> 3) ^ (lp & 7)) << 3) + (ci & 7)] = (__bf16)v;
    }
    __syncthreads();

    // MFMA main: contraction over 3 taps x 64 ci
    f32x4 acc[2][8] = {};
    #pragma unroll
    for (int kk = 0; kk < 6; ++kk) {
        const int k = kk >> 1, s2 = kk & 1;
        #pragma unroll
        for (int n = 0; n < 8; ++n) {
            const int lp  = wl * 128 + n * 16 + l15 + k;   // tap-shifted row
            const int blk = (s2 * 4 + g) ^ (lp & 7);
            bf16x8 bfr = *(const bf16x8*)(xt + lp * 64 + blk * 8);
            acc[0][n] = __builtin_amdgcn_mfma_f32_16x16x32_bf16(af[0][kk], bfr, acc[0][n], 0, 0, 0);
            acc[1][n] = __builtin_amdgcn_mfma_f32_16x16x32_bf16(af[1][kk], bfr, acc[1][n], 0, 0, 0);
        }
    }

    // epilogue: + base_b, LDS transpose, coalesced f32x4 stores
    #pragma unroll
    for (int m = 0; m < 2; ++m) {
        __syncthreads();   // xt reads (m=0) / ot reads (m=1) complete
        const int r0 = wco * 16 + g * 4;             // staged rows r0..r0+3
        #pragma unroll
        for (int j = 0; j < 4; ++j) {
            const int co = wco * 32 + m * 16 + g * 4 + j;
            const float bb = base_b[co];
            #pragma unroll
            for (int n = 0; n < 8; ++n)
                ot[(r0 + j) * 258 + wl * 128 + n * 16 + l15] = acc[m][n][j] + bb;
        }
        __syncthreads();
        #pragma unroll
        for (int it = 0; it < 8; ++it) {
            const int c   = t + it * 256;            // 0..2047
            const int co2 = c >> 6;                  // staged row 0..31
            const int lr4 = c & 63;                  // f32x4 index in row
            f32x4 v = *(const f32x4*)(ot + co2 * 258 + lr4 * 4);
            const int co = (co2 >> 4) * 32 + m * 16 + (co2 & 15);
            *(f32x4*)(out + (size_t)(b * NCOUT + co) * LLEN + l0 + lr4 * 4) = v;
        }
    }
}

// ---------------------------------------------------------------------------
extern "C" void kernel_launch(void* const* d_in, const int* in_sizes, int n_in,
                              void* d_out, int out_size, void* d_ws, size_t ws_size,
                              hipStream_t stream)
{
    const float* X      = (const float*)d_in[0];
    const float* a_emb  = (const float*)d_in[1];
    const float* b_emb  = (const float*)d_in[2];
    const float* A_w1   = (const float*)d_in[3];
    const float* A_b1   = (const float*)d_in[4];
    const float* A_g    = (const float*)d_in[5];
    const float* A_beta = (const float*)d_in[6];
    const float* A_w2   = (const float*)d_in[7];
    const float* A_b2   = (const float*)d_in[8];
    const float* B_w1   = (const float*)d_in[9];
    const float* B_b1   = (const float*)d_in[10];
    const float* B_g    = (const float*)d_in[11];
    const float* B_beta = (const float*)d_in[12];
    const float* B_w2   = (const float*)d_in[13];
    const float* B_b2   = (const float*)d_in[14];
    const float* base_w = (const float*)d_in[15];
    const float* base_b = (const float*)d_in[16];

    float* out = (float*)d_out;   // reference output dtype is float32

    factors_kernel<<<BS, 256, 0, stream>>>(a_emb, b_emb,
        A_w1, A_b1, A_g, A_beta, A_w2, A_b2,
        B_w1, B_b1, B_g, B_beta, B_w2, B_b2,
        base_w);

    conv_kernel<<<BS * (LLEN / NT), 256, 0, stream>>>(X, base_b, out);
}

// Round 6
// 186.234 us; speedup vs baseline: 1.3330x; 1.2581x over previous
//
#include <hip/hip_runtime.h>
#include <hip/hip_bf16.h>

#define BS    128
#define NCIN  64
#define NCOUT 64
#define LLEN  8192
#define NK    3
#define NR    8
#define NEMB  256
#define NHID  256
#define WPS   (NCOUT * NCIN * NK)   // 12288 weights per sample
#define NT    256                   // l-positions per conv block

typedef __attribute__((ext_vector_type(4))) float f32x4;
typedef __attribute__((ext_vector_type(8))) __bf16 bf16x8;

// Static device scratch (fully rewritten every call).
__device__ float  g_A[BS * 512];    // A factors [b][ci*8+r]
__device__ float  g_B[BS * 1536];   // B factors [b][r*192+co*3+k]
__device__ __bf16 g_Wb[BS * WPS];   // W_eff bf16 [b][k*4096+co*64+ci]

// ---------------------------------------------------------------------------
// Kernel 1: MLP branches. 256 blocks: block = (branch, sample).
// branch 0: a_emb -> A factors (512 out);  branch 1: b_emb -> B factors (1536).
// ---------------------------------------------------------------------------
__global__ __launch_bounds__(256) void mlp_kernel(
    const float* __restrict__ a_emb, const float* __restrict__ b_emb,
    const float* __restrict__ A_w1, const float* __restrict__ A_b1,
    const float* __restrict__ A_g,  const float* __restrict__ A_beta,
    const float* __restrict__ A_w2, const float* __restrict__ A_b2,
    const float* __restrict__ B_w1, const float* __restrict__ B_b1,
    const float* __restrict__ B_g,  const float* __restrict__ B_beta,
    const float* __restrict__ B_w2, const float* __restrict__ B_b2)
{
    __shared__ __align__(16) float emb_s[NEMB];
    __shared__ __align__(16) float h_s[NHID];

    const int t      = threadIdx.x;
    const int branch = blockIdx.x >> 7;
    const int b      = blockIdx.x & 127;

    const float* emb  = (branch ? b_emb : a_emb) + (size_t)b * NEMB;
    const float* w1   = branch ? B_w1 : A_w1;
    const float* b1   = branch ? B_b1 : A_b1;
    const float* gg   = branch ? B_g  : A_g;
    const float* bt   = branch ? B_beta : A_beta;
    const float* w2   = branch ? B_w2 : A_w2;
    const float* b2   = branch ? B_b2 : A_b2;
    float* outp       = (branch ? g_B : g_A) + (size_t)b * (branch ? 1536 : 512);
    const int nloops  = branch ? 6 : 2;

    emb_s[t] = emb[t];
    __syncthreads();

    // hidden: Linear + BN(eval, mean=0 var=1) + exact GELU
    {
        float acc = b1[t];
        const f32x4* wr = (const f32x4*)(w1 + (size_t)t * NEMB);
        const f32x4* es = (const f32x4*)emb_s;
        for (int e = 0; e < NEMB / 4; ++e) {
            f32x4 w = wr[e], a = es[e];
            acc += w[0]*a[0] + w[1]*a[1] + w[2]*a[2] + w[3]*a[3];
        }
        float h = acc * (gg[t] * (1.0f / sqrtf(1.0f + 1e-5f))) + bt[t];
        h = 0.5f * h * (1.0f + erff(h * 0.70710678118654752f));
        h_s[t] = h;
    }
    __syncthreads();

    // outputs
    for (int oo = 0; oo < nloops; ++oo) {
        const int o = oo * 256 + t;
        float acc = b2[o];
        const f32x4* wr = (const f32x4*)(w2 + (size_t)o * NHID);
        const f32x4* hs = (const f32x4*)h_s;
        for (int e = 0; e < NHID / 4; ++e) {
            f32x4 w = wr[e], h = hs[e];
            acc += w[0]*h[0] + w[1]*h[1] + w[2]*h[2] + w[3]*h[3];
        }
        outp[o] = acc;
    }
}

// ---------------------------------------------------------------------------
// Kernel 2: assemble W_eff = base_w + A·B  (bf16, [b][k*4096+co*64+ci]).
// 512 blocks: block = (b, quarter). w enumerates k*4096+co*64+ci.
// ---------------------------------------------------------------------------
__global__ __launch_bounds__(256) void assemble_kernel(const float* __restrict__ base_w)
{
    const int b  = blockIdx.x >> 2;
    const int q  = blockIdx.x & 3;
    const int t  = threadIdx.x;
    const int ci = t & 63;

    float Ar[NR];
    const f32x4* Ap = (const f32x4*)(g_A + (size_t)b * 512 + ci * NR);
    f32x4 a0 = Ap[0], a1 = Ap[1];
    Ar[0]=a0[0]; Ar[1]=a0[1]; Ar[2]=a0[2]; Ar[3]=a0[3];
    Ar[4]=a1[0]; Ar[5]=a1[1]; Ar[6]=a1[2]; Ar[7]=a1[3];

    const float* Bp = g_B + (size_t)b * 1536;
    for (int i = 0; i < 12; ++i) {
        const int w  = q * 3072 + i * 256 + t;
        const int k  = w >> 12;            // wave-uniform
        const int co = (w >> 6) & 63;      // wave-uniform
        float v = base_w[(size_t)(co * 64 + ci) * 3 + k];
        #pragma unroll
        for (int r = 0; r < NR; ++r) v += Ar[r] * Bp[r * 192 + co * 3 + k];
        g_Wb[(size_t)b * WPS + w] = (__bf16)v;
    }
}

// ---------------------------------------------------------------------------
// Kernel 3: per-sample conv as MFMA GEMM. Block = (b, 256-l tile).
// LDS: X tile transposed [lp][ci] bf16, XOR-swizzled with (lp&7)^((lp>>3)&7)
// (the extra lp>>3 term breaks the wave-uniform-ci write conflict: 32-way -> 8-way).
// Reused as f32 [32][258] for the coalesced-store epilogue.
// ---------------------------------------------------------------------------
__global__ __launch_bounds__(256) void conv_kernel(
    const float* __restrict__ X, const float* __restrict__ base_b,
    float* __restrict__ out)
{
    __shared__ __align__(16) unsigned char smem[33024];  // = (NT+2)*64*2 = 32*258*4
    __bf16* xt = (__bf16*)smem;
    float*  ot = (float*)smem;

    const int t    = threadIdx.x;
    const int b    = blockIdx.x >> 5;    // 32 tiles per sample
    const int tile = blockIdx.x & 31;
    const int l0   = tile * NT;
    const int lane = t & 63;
    const int wave = t >> 6;
    const int g    = lane >> 4;
    const int l15  = lane & 15;
    const int wco  = wave >> 1;          // which 32 co
    const int wl   = wave & 1;           // which 128 l

    // A fragments (weights) into registers
    bf16x8 af[2][6];
    {
        const __bf16* wb = g_Wb + (size_t)b * WPS;
        #pragma unroll
        for (int m = 0; m < 2; ++m)
            #pragma unroll
            for (int kk = 0; kk < 6; ++kk) {
                const int k = kk >> 1, s2 = kk & 1;
                const int co = wco * 32 + m * 16 + l15;
                const int cc = s2 * 32 + g * 8;
                af[m][kk] = *(const bf16x8*)(wb + k * 4096 + co * 64 + cc);
            }
    }

    // stage X tile (transposed + swizzled, f32 -> bf16)
    for (int p = 0; p < 16; ++p) {
        const int ci = p * 4 + wave;
        const int f4 = lane;
        f32x4 v = *(const f32x4*)(X + (size_t)(b * NCIN + ci) * LLEN + l0 + f4 * 4);
        #pragma unroll
        for (int j = 0; j < 4; ++j) {
            const int lp  = f4 * 4 + j + 1;
            const int blk = (ci >> 3) ^ (lp & 7) ^ ((lp >> 3) & 7);
            xt[lp * 64 + blk * 8 + (ci & 7)] = (__bf16)v[j];
        }
    }
    if (t < 128) {  // halo columns (pad = 1)
        const int ci    = t & 63;
        const int right = t >> 6;
        const int gl    = right ? (l0 + NT) : (l0 - 1);
        const int lp    = right ? (NT + 1) : 0;
        const float v   = (gl >= 0 && gl < LLEN) ? X[(size_t)(b * NCIN + ci) * LLEN + gl] : 0.0f;
        const int blk   = (ci >> 3) ^ (lp & 7) ^ ((lp >> 3) & 7);
        xt[lp * 64 + blk * 8 + (ci & 7)] = (__bf16)v;
    }
    __syncthreads();

    // MFMA main: contraction over 3 taps x 64 ci
    f32x4 acc[2][8] = {};
    #pragma unroll
    for (int kk = 0; kk < 6; ++kk) {
        const int k = kk >> 1, s2 = kk & 1;
        #pragma unroll
        for (int n = 0; n < 8; ++n) {
            const int lp  = wl * 128 + n * 16 + l15 + k;   // tap-shifted row
            const int blk = (s2 * 4 + g) ^ (lp & 7) ^ ((lp >> 3) & 7);
            bf16x8 bfr = *(const bf16x8*)(xt + lp * 64 + blk * 8);
            acc[0][n] = __builtin_amdgcn_mfma_f32_16x16x32_bf16(af[0][kk], bfr, acc[0][n], 0, 0, 0);
            acc[1][n] = __builtin_amdgcn_mfma_f32_16x16x32_bf16(af[1][kk], bfr, acc[1][n], 0, 0, 0);
        }
    }

    // epilogue: + base_b, LDS transpose, coalesced f32x4 stores
    #pragma unroll
    for (int m = 0; m < 2; ++m) {
        __syncthreads();   // xt reads (m=0) / ot reads (m=1) complete
        const int r0 = wco * 16 + g * 4;             // staged rows r0..r0+3
        #pragma unroll
        for (int j = 0; j < 4; ++j) {
            const int co = wco * 32 + m * 16 + g * 4 + j;
            const float bb = base_b[co];
            #pragma unroll
            for (int n = 0; n < 8; ++n)
                ot[(r0 + j) * 258 + wl * 128 + n * 16 + l15] = acc[m][n][j] + bb;
        }
        __syncthreads();
        #pragma unroll
        for (int it = 0; it < 8; ++it) {
            const int c   = t + it * 256;            // 0..2047
            const int co2 = c >> 6;                  // staged row 0..31
            const int lr4 = c & 63;                  // f32x4 index in row
            f32x4 v = *(const f32x4*)(ot + co2 * 258 + lr4 * 4);
            const int co = (co2 >> 4) * 32 + m * 16 + (co2 & 15);
            *(f32x4*)(out + (size_t)(b * NCOUT + co) * LLEN + l0 + lr4 * 4) = v;
        }
    }
}

// ---------------------------------------------------------------------------
extern "C" void kernel_launch(void* const* d_in, const int* in_sizes, int n_in,
                              void* d_out, int out_size, void* d_ws, size_t ws_size,
                              hipStream_t stream)
{
    const float* X      = (const float*)d_in[0];
    const float* a_emb  = (const float*)d_in[1];
    const float* b_emb  = (const float*)d_in[2];
    const float* A_w1   = (const float*)d_in[3];
    const float* A_b1   = (const float*)d_in[4];
    const float* A_g    = (const float*)d_in[5];
    const float* A_beta = (const float*)d_in[6];
    const float* A_w2   = (const float*)d_in[7];
    const float* A_b2   = (const float*)d_in[8];
    const float* B_w1   = (const float*)d_in[9];
    const float* B_b1   = (const float*)d_in[10];
    const float* B_g    = (const float*)d_in[11];
    const float* B_beta = (const float*)d_in[12];
    const float* B_w2   = (const float*)d_in[13];
    const float* B_b2   = (const float*)d_in[14];
    const float* base_w = (const float*)d_in[15];
    const float* base_b = (const float*)d_in[16];

    float* out = (float*)d_out;   // reference output dtype is float32

    mlp_kernel<<<2 * BS, 256, 0, stream>>>(a_emb, b_emb,
        A_w1, A_b1, A_g, A_beta, A_w2, A_b2,
        B_w1, B_b1, B_g, B_beta, B_w2, B_b2);

    assemble_kernel<<<4 * BS, 256, 0, stream>>>(base_w);

    conv_kernel<<<BS * (LLEN / NT), 256, 0, stream>>>(X, base_b, out);
}

// Round 7
// 186.077 us; speedup vs baseline: 1.3342x; 1.0008x over previous
//
#include <hip/hip_runtime.h>
#include <hip/hip_bf16.h>

#define BS    128
#define NCIN  64
#define NCOUT 64
#define LLEN  8192
#define NK    3
#define NR    8
#define NEMB  256
#define NHID  256
#define WPS   (NCOUT * NCIN * NK)   // 12288 weights per sample
#define NT    256                   // l-positions per conv block

typedef __attribute__((ext_vector_type(4))) float f32x4;
typedef __attribute__((ext_vector_type(8))) __bf16 bf16x8;

// Static device scratch (fully rewritten every call).
__device__ float  g_A[BS * 512];    // A factors [b][ci*8+r]
__device__ float  g_B[BS * 1536];   // B factors [b][r*192+co*3+k]
__device__ __bf16 g_Wb[BS * WPS];   // W_eff bf16 [b][k*4096+co*64+ci]

// ---------------------------------------------------------------------------
// Kernel 1: MLP branches. 256 blocks: block = (branch, sample).
// ---------------------------------------------------------------------------
__global__ __launch_bounds__(256) void mlp_kernel(
    const float* __restrict__ a_emb, const float* __restrict__ b_emb,
    const float* __restrict__ A_w1, const float* __restrict__ A_b1,
    const float* __restrict__ A_g,  const float* __restrict__ A_beta,
    const float* __restrict__ A_w2, const float* __restrict__ A_b2,
    const float* __restrict__ B_w1, const float* __restrict__ B_b1,
    const float* __restrict__ B_g,  const float* __restrict__ B_beta,
    const float* __restrict__ B_w2, const float* __restrict__ B_b2)
{
    __shared__ __align__(16) float emb_s[NEMB];
    __shared__ __align__(16) float h_s[NHID];

    const int t      = threadIdx.x;
    const int branch = blockIdx.x >> 7;
    const int b      = blockIdx.x & 127;

    const float* emb  = (branch ? b_emb : a_emb) + (size_t)b * NEMB;
    const float* w1   = branch ? B_w1 : A_w1;
    const float* b1   = branch ? B_b1 : A_b1;
    const float* gg   = branch ? B_g  : A_g;
    const float* bt   = branch ? B_beta : A_beta;
    const float* w2   = branch ? B_w2 : A_w2;
    const float* b2   = branch ? B_b2 : A_b2;
    float* outp       = (branch ? g_B : g_A) + (size_t)b * (branch ? 1536 : 512);
    const int nloops  = branch ? 6 : 2;

    emb_s[t] = emb[t];
    __syncthreads();

    // hidden: Linear + BN(eval, mean=0 var=1) + exact GELU
    {
        float acc = b1[t];
        const f32x4* wr = (const f32x4*)(w1 + (size_t)t * NEMB);
        const f32x4* es = (const f32x4*)emb_s;
        for (int e = 0; e < NEMB / 4; ++e) {
            f32x4 w = wr[e], a = es[e];
            acc += w[0]*a[0] + w[1]*a[1] + w[2]*a[2] + w[3]*a[3];
        }
        float h = acc * (gg[t] * (1.0f / sqrtf(1.0f + 1e-5f))) + bt[t];
        h = 0.5f * h * (1.0f + erff(h * 0.70710678118654752f));
        h_s[t] = h;
    }
    __syncthreads();

    // outputs
    for (int oo = 0; oo < nloops; ++oo) {
        const int o = oo * 256 + t;
        float acc = b2[o];
        const f32x4* wr = (const f32x4*)(w2 + (size_t)o * NHID);
        const f32x4* hs = (const f32x4*)h_s;
        for (int e = 0; e < NHID / 4; ++e) {
            f32x4 w = wr[e], h = hs[e];
            acc += w[0]*h[0] + w[1]*h[1] + w[2]*h[2] + w[3]*h[3];
        }
        outp[o] = acc;
    }
}

// ---------------------------------------------------------------------------
// Kernel 2: assemble W_eff = base_w + A·B  (bf16, [b][k*4096+co*64+ci]).
// ---------------------------------------------------------------------------
__global__ __launch_bounds__(256) void assemble_kernel(const float* __restrict__ base_w)
{
    const int b  = blockIdx.x >> 2;
    const int q  = blockIdx.x & 3;
    const int t  = threadIdx.x;
    const int ci = t & 63;

    float Ar[NR];
    const f32x4* Ap = (const f32x4*)(g_A + (size_t)b * 512 + ci * NR);
    f32x4 a0 = Ap[0], a1 = Ap[1];
    Ar[0]=a0[0]; Ar[1]=a0[1]; Ar[2]=a0[2]; Ar[3]=a0[3];
    Ar[4]=a1[0]; Ar[5]=a1[1]; Ar[6]=a1[2]; Ar[7]=a1[3];

    const float* Bp = g_B + (size_t)b * 1536;
    for (int i = 0; i < 12; ++i) {
        const int w  = q * 3072 + i * 256 + t;
        const int k  = w >> 12;
        const int co = (w >> 6) & 63;
        float v = base_w[(size_t)(co * 64 + ci) * 3 + k];
        #pragma unroll
        for (int r = 0; r < NR; ++r) v += Ar[r] * Bp[r * 192 + co * 3 + k];
        g_Wb[(size_t)b * WPS + w] = (__bf16)v;
    }
}

// ---------------------------------------------------------------------------
// Kernel 3: per-sample conv as MFMA GEMM. Block = (b, 256-l tile).
// LDS: X tile transposed [lp][ci] bf16, XOR-swizzled blk = (ci>>3)^(lp&7)^((lp>>3)&7).
// Staging: 8ci x 8l micro-tile per thread -> 8x ds_write_b128, conflict-free.
// LDS reused as f32 [32][258] for the coalesced-store epilogue.
// ---------------------------------------------------------------------------
__global__ __launch_bounds__(256) void conv_kernel(
    const float* __restrict__ X, const float* __restrict__ base_b,
    float* __restrict__ out)
{
    __shared__ __align__(16) unsigned char smem[33024];  // = (NT+2)*64*2 = 32*258*4
    __bf16* xt = (__bf16*)smem;
    float*  ot = (float*)smem;

    const int t    = threadIdx.x;
    const int b    = blockIdx.x >> 5;    // 32 tiles per sample
    const int tile = blockIdx.x & 31;
    const int l0   = tile * NT;
    const int lane = t & 63;
    const int wave = t >> 6;
    const int g    = lane >> 4;
    const int l15  = lane & 15;
    const int wco  = wave >> 1;          // which 32 co
    const int wl   = wave & 1;           // which 128 l

    // A fragments (weights) into registers
    bf16x8 af[2][6];
    {
        const __bf16* wb = g_Wb + (size_t)b * WPS;
        #pragma unroll
        for (int m = 0; m < 2; ++m)
            #pragma unroll
            for (int kk = 0; kk < 6; ++kk) {
                const int k = kk >> 1, s2 = kk & 1;
                const int co = wco * 32 + m * 16 + l15;
                const int cc = s2 * 32 + g * 8;
                af[m][kk] = *(const bf16x8*)(wb + k * 4096 + co * 64 + cc);
            }
    }

    // ---- stage X tile: 8ci x 8l micro-tile per thread ----
    {
        const int lb = t & 31;           // l-block of 8
        const int cb = t >> 5;           // ci-block of 8
        f32x4 v[8][2];
        const float* xb = X + (size_t)b * NCIN * LLEN + l0 + lb * 8;
        #pragma unroll
        for (int c = 0; c < 8; ++c) {
            const float* xr = xb + (size_t)(cb * 8 + c) * LLEN;
            v[c][0] = *(const f32x4*)(xr);
            v[c][1] = *(const f32x4*)(xr + 4);
        }
        #pragma unroll
        for (int j = 0; j < 8; ++j) {
            const int lp = lb * 8 + j + 1;
            bf16x8 w;
            #pragma unroll
            for (int c = 0; c < 8; ++c) w[c] = (__bf16)v[c][j >> 2][j & 3];
            const int blk = cb ^ (lp & 7) ^ ((lp >> 3) & 7);
            *(bf16x8*)(xt + lp * 64 + blk * 8) = w;
        }
    }
    if (t < 128) {  // halo columns (pad = 1)
        const int ci    = t & 63;
        const int right = t >> 6;
        const int gl    = right ? (l0 + NT) : (l0 - 1);
        const int lp    = right ? (NT + 1) : 0;
        const float v   = (gl >= 0 && gl < LLEN) ? X[(size_t)(b * NCIN + ci) * LLEN + gl] : 0.0f;
        const int blk   = (ci >> 3) ^ (lp & 7) ^ ((lp >> 3) & 7);
        xt[lp * 64 + blk * 8 + (ci & 7)] = (__bf16)v;
    }
    __syncthreads();

    // MFMA main: contraction over 3 taps x 64 ci
    f32x4 acc[2][8] = {};
    #pragma unroll
    for (int kk = 0; kk < 6; ++kk) {
        const int k = kk >> 1, s2 = kk & 1;
        #pragma unroll
        for (int n = 0; n < 8; ++n) {
            const int lp  = wl * 128 + n * 16 + l15 + k;   // tap-shifted row
            const int blk = (s2 * 4 + g) ^ (lp & 7) ^ ((lp >> 3) & 7);
            bf16x8 bfr = *(const bf16x8*)(xt + lp * 64 + blk * 8);
            acc[0][n] = __builtin_amdgcn_mfma_f32_16x16x32_bf16(af[0][kk], bfr, acc[0][n], 0, 0, 0);
            acc[1][n] = __builtin_amdgcn_mfma_f32_16x16x32_bf16(af[1][kk], bfr, acc[1][n], 0, 0, 0);
        }
    }

    // epilogue: + base_b, LDS transpose, coalesced f32x4 stores
    #pragma unroll
    for (int m = 0; m < 2; ++m) {
        __syncthreads();   // xt reads (m=0) / ot reads (m=1) complete
        const int r0 = wco * 16 + g * 4;             // staged rows r0..r0+3
        #pragma unroll
        for (int j = 0; j < 4; ++j) {
            const int co = wco * 32 + m * 16 + g * 4 + j;
            const float bb = base_b[co];
            #pragma unroll
            for (int n = 0; n < 8; ++n)
                ot[(r0 + j) * 258 + wl * 128 + n * 16 + l15] = acc[m][n][j] + bb;
        }
        __syncthreads();
        #pragma unroll
        for (int it = 0; it < 8; ++it) {
            const int c   = t + it * 256;            // 0..2047
            const int co2 = c >> 6;                  // staged row 0..31
            const int lr4 = c & 63;                  // f32x4 index in row
            f32x4 v = *(const f32x4*)(ot + co2 * 258 + lr4 * 4);
            const int co = (co2 >> 4) * 32 + m * 16 + (co2 & 15);
            *(f32x4*)(out + (size_t)(b * NCOUT + co) * LLEN + l0 + lr4 * 4) = v;
        }
    }
}

// ---------------------------------------------------------------------------
extern "C" void kernel_launch(void* const* d_in, const int* in_sizes, int n_in,
                              void* d_out, int out_size, void* d_ws, size_t ws_size,
                              hipStream_t stream)
{
    const float* X      = (const float*)d_in[0];
    const float* a_emb  = (const float*)d_in[1];
    const float* b_emb  = (const float*)d_in[2];
    const float* A_w1   = (const float*)d_in[3];
    const float* A_b1   = (const float*)d_in[4];
    const float* A_g    = (const float*)d_in[5];
    const float* A_beta = (const float*)d_in[6];
    const float* A_w2   = (const float*)d_in[7];
    const float* A_b2   = (const float*)d_in[8];
    const float* B_w1   = (const float*)d_in[9];
    const float* B_b1   = (const float*)d_in[10];
    const float* B_g    = (const float*)d_in[11];
    const float* B_beta = (const float*)d_in[12];
    const float* B_w2   = (const float*)d_in[13];
    const float* B_b2   = (const float*)d_in[14];
    const float* base_w = (const float*)d_in[15];
    const float* base_b = (const float*)d_in[16];

    float* out = (float*)d_out;   // reference output dtype is float32

    mlp_kernel<<<2 * BS, 256, 0, stream>>>(a_emb, b_emb,
        A_w1, A_b1, A_g, A_beta, A_w2, A_b2,
        B_w1, B_b1, B_g, B_beta, B_w2, B_b2);

    assemble_kernel<<<4 * BS, 256, 0, stream>>>(base_w);

    conv_kernel<<<BS * (LLEN / NT), 256, 0, stream>>>(X, base_b, out);
}